// Round 4
// baseline (314.834 us; speedup 1.0000x reference)
//
#include <hip/hip_runtime.h>
#include <math.h>

typedef float f32x4 __attribute__((ext_vector_type(4)));

// ---------------------------------------------------------------------------
// Prep (256 blocks x 256 thr): per node i, feature f:
//   Wh  = h @ W                         (K=128 dot)
//   s1  = adj @ a[:64], s2 = adj @ a[64:]
//   EA1 = exp(s1), EA2 = exp(0.2*s1)
//   EB1 = adj[i,f]>0 ? exp(s2) : 0, EB2 = adj[i,f]>0 ? exp(0.2*s2) : 0
// Identity: exp(leakyrelu(s1+s2)) = max(EA1*EB1, EA2*EB2); mask -> exact 0.
// ---------------------------------------------------------------------------
__global__ __launch_bounds__(256) void gat_prep(
    const float* __restrict__ h, const float* __restrict__ adj,
    const float* __restrict__ W, const float* __restrict__ a,
    float* __restrict__ Wh, float* __restrict__ EA1, float* __restrict__ EA2,
    float* __restrict__ EB1, float* __restrict__ EB2)
{
    const int t = threadIdx.x;
    const int f = t & 63;
    const int i = (blockIdx.x << 2) + (t >> 6);   // wave-uniform row

    const float* __restrict__ hrow = h + i * 128;
    const float* __restrict__ arow = adj + i * 64;

    float wh = 0.0f;
    #pragma unroll 8
    for (int k = 0; k < 128; ++k) wh = fmaf(hrow[k], W[k * 64 + f], wh);
    Wh[i * 64 + f] = wh;

    float v1 = 0.0f, v2 = 0.0f;
    #pragma unroll 8
    for (int k = 0; k < 64; ++k) {
        const float av = arow[k];
        v1 = fmaf(av, a[k * 64 + f], v1);
        v2 = fmaf(av, a[(64 + k) * 64 + f], v2);
    }
    EA1[i * 64 + f] = __expf(v1);
    EA2[i * 64 + f] = __expf(0.2f * v1);
    const bool m = arow[f] > 0.0f;                // source-node mask adj[j,f]>0
    EB1[i * 64 + f] = m ? __expf(v2) : 0.0f;
    EB2[i * 64 + f] = m ? __expf(0.2f * v2) : 0.0f;
}

// ---------------------------------------------------------------------------
// Main (512 blocks x 512 thr): block handles TWO destination rows i0,i1 —
// every b1/b2/wv load is reused for both rows (halves L2 read traffic).
// fg = t&15 (4 features), jo = t>>4 (32 j-offsets): wave stores 1KiB
// contiguous per row per iteration.
// Pass 1: Z[r][f] = sum_j max(EA1*EB1, EA2*EB2)   (no exp in loop)
// Pass 2: att = max(s1*EB1, s2*EB2), s{1,2} = EA{1,2}/Z prefolded;
//         plain streaming stores + h_prime fma accumulate.
// ---------------------------------------------------------------------------
__global__ __launch_bounds__(512, 4) void gat_attn(
    const float* __restrict__ EA1, const float* __restrict__ EA2,
    const float* __restrict__ EB1, const float* __restrict__ EB2,
    const float* __restrict__ Wh,
    float* __restrict__ out_hp, float* __restrict__ out_att)
{
    __shared__ float red[2][32][64];
    __shared__ float zinv[2][64];

    const int t  = threadIdx.x;
    const int fg = t & 15;
    const int jo = t >> 4;          // 0..31
    const int fb = fg << 2;
    const int i0 = blockIdx.x << 1;

    const f32x4 a1r0 = *reinterpret_cast<const f32x4*>(EA1 + (i0 + 0) * 64 + fb);
    const f32x4 a2r0 = *reinterpret_cast<const f32x4*>(EA2 + (i0 + 0) * 64 + fb);
    const f32x4 a1r1 = *reinterpret_cast<const f32x4*>(EA1 + (i0 + 1) * 64 + fb);
    const f32x4 a2r1 = *reinterpret_cast<const f32x4*>(EA2 + (i0 + 1) * 64 + fb);

    // ---- pass 1: Z for both rows ----
    f32x4 z0 = {0.f, 0.f, 0.f, 0.f};
    f32x4 z1 = {0.f, 0.f, 0.f, 0.f};
    #pragma unroll 4
    for (int jb = 0; jb < 1024; jb += 32) {
        const int j = jb + jo;
        const f32x4 b1 = *reinterpret_cast<const f32x4*>(EB1 + j * 64 + fb);
        const f32x4 b2 = *reinterpret_cast<const f32x4*>(EB2 + j * 64 + fb);
        z0.x += fmaxf(a1r0.x * b1.x, a2r0.x * b2.x);
        z0.y += fmaxf(a1r0.y * b1.y, a2r0.y * b2.y);
        z0.z += fmaxf(a1r0.z * b1.z, a2r0.z * b2.z);
        z0.w += fmaxf(a1r0.w * b1.w, a2r0.w * b2.w);
        z1.x += fmaxf(a1r1.x * b1.x, a2r1.x * b2.x);
        z1.y += fmaxf(a1r1.y * b1.y, a2r1.y * b2.y);
        z1.z += fmaxf(a1r1.z * b1.z, a2r1.z * b2.z);
        z1.w += fmaxf(a1r1.w * b1.w, a2r1.w * b2.w);
    }
    *reinterpret_cast<f32x4*>(&red[0][jo][fb]) = z0;
    *reinterpret_cast<f32x4*>(&red[1][jo][fb]) = z1;
    __syncthreads();
    if (t < 128) {
        const int r = t >> 6, f = t & 63;
        float z = 0.0f;
        #pragma unroll
        for (int o = 0; o < 32; ++o) z += red[r][o][f];
        zinv[r][f] = 1.0f / z;
    }
    __syncthreads();

    f32x4 s1r0, s2r0, s1r1, s2r1;   // fold 1/Z into per-row terms once
    {
        const f32x4 v0 = *reinterpret_cast<const f32x4*>(&zinv[0][fb]);
        const f32x4 v1 = *reinterpret_cast<const f32x4*>(&zinv[1][fb]);
        s1r0.x = a1r0.x * v0.x; s1r0.y = a1r0.y * v0.y; s1r0.z = a1r0.z * v0.z; s1r0.w = a1r0.w * v0.w;
        s2r0.x = a2r0.x * v0.x; s2r0.y = a2r0.y * v0.y; s2r0.z = a2r0.z * v0.z; s2r0.w = a2r0.w * v0.w;
        s1r1.x = a1r1.x * v1.x; s1r1.y = a1r1.y * v1.y; s1r1.z = a1r1.z * v1.z; s1r1.w = a1r1.w * v1.w;
        s2r1.x = a2r1.x * v1.x; s2r1.y = a2r1.y * v1.y; s2r1.z = a2r1.z * v1.z; s2r1.w = a2r1.w * v1.w;
    }

    // ---- pass 2: stream attention (2 rows) + accumulate h_prime ----
    f32x4 h0 = {0.f, 0.f, 0.f, 0.f};
    f32x4 h1 = {0.f, 0.f, 0.f, 0.f};
    float* __restrict__ o0 = out_att + (size_t)(i0 + 0) * 65536 + fb;
    float* __restrict__ o1 = out_att + (size_t)(i0 + 1) * 65536 + fb;
    #pragma unroll 4
    for (int jb = 0; jb < 1024; jb += 32) {
        const int j = jb + jo;
        const f32x4 b1 = *reinterpret_cast<const f32x4*>(EB1 + j * 64 + fb);
        const f32x4 b2 = *reinterpret_cast<const f32x4*>(EB2 + j * 64 + fb);
        const f32x4 wv = *reinterpret_cast<const f32x4*>(Wh  + j * 64 + fb);
        f32x4 oA, oB;
        oA.x = fmaxf(s1r0.x * b1.x, s2r0.x * b2.x);
        oA.y = fmaxf(s1r0.y * b1.y, s2r0.y * b2.y);
        oA.z = fmaxf(s1r0.z * b1.z, s2r0.z * b2.z);
        oA.w = fmaxf(s1r0.w * b1.w, s2r0.w * b2.w);
        oB.x = fmaxf(s1r1.x * b1.x, s2r1.x * b2.x);
        oB.y = fmaxf(s1r1.y * b1.y, s2r1.y * b2.y);
        oB.z = fmaxf(s1r1.z * b1.z, s2r1.z * b2.z);
        oB.w = fmaxf(s1r1.w * b1.w, s2r1.w * b2.w);
        h0.x = fmaf(oA.x, wv.x, h0.x); h0.y = fmaf(oA.y, wv.y, h0.y);
        h0.z = fmaf(oA.z, wv.z, h0.z); h0.w = fmaf(oA.w, wv.w, h0.w);
        h1.x = fmaf(oB.x, wv.x, h1.x); h1.y = fmaf(oB.y, wv.y, h1.y);
        h1.z = fmaf(oB.z, wv.z, h1.z); h1.w = fmaf(oB.w, wv.w, h1.w);
        *reinterpret_cast<f32x4*>(o0 + j * 64) = oA;
        *reinterpret_cast<f32x4*>(o1 + j * 64) = oB;
    }

    *reinterpret_cast<f32x4*>(&red[0][jo][fb]) = h0;   // safe: after barrier 2
    *reinterpret_cast<f32x4*>(&red[1][jo][fb]) = h1;
    __syncthreads();
    if (t < 128) {
        const int r = t >> 6, f = t & 63;
        float v = 0.0f;
        #pragma unroll
        for (int o = 0; o < 32; ++o) v += red[r][o][f];
        out_hp[(i0 + r) * 64 + f] = (v > 0.0f) ? v : expm1f(v);
    }
}

extern "C" void kernel_launch(void* const* d_in, const int* in_sizes, int n_in,
                              void* d_out, int out_size, void* d_ws, size_t ws_size,
                              hipStream_t stream) {
    const float* h   = (const float*)d_in[0];   // (1024, 128)
    const float* adj = (const float*)d_in[1];   // (1024, 64)
    const float* W   = (const float*)d_in[2];   // (128, 64)
    const float* a   = (const float*)d_in[3];   // (128, 64)

    float* ws  = (float*)d_ws;                  // 1.25 MiB scratch used
    float* Wh  = ws;                            // (1024, 64)
    float* EA1 = ws + 65536;
    float* EA2 = ws + 131072;
    float* EB1 = ws + 196608;
    float* EB2 = ws + 262144;

    float* out     = (float*)d_out;
    float* out_hp  = out;                       // elu(h_prime): 65536 floats
    float* out_att = out + 65536;               // attention: 1024*1024*64

    gat_prep<<<256, 256, 0, stream>>>(h, adj, W, a, Wh, EA1, EA2, EB1, EB2);
    gat_attn<<<512, 512, 0, stream>>>(EA1, EA2, EB1, EB2, Wh, out_hp, out_att);
}

// Round 5
// 280.423 us; speedup vs baseline: 1.1227x; 1.1227x over previous
//
#include <hip/hip_runtime.h>
#include <math.h>

typedef float f32x4 __attribute__((ext_vector_type(4)));

// ---------------------------------------------------------------------------
// Prep (256 blocks x 256 thr): per node i, feature f:
//   Wh  = h @ W                         (K=128 dot)
//   s1  = adj @ a[:64], s2 = adj @ a[64:]
//   EA1 = exp(s1), EA2 = exp(0.2*s1)
//   EB1 = adj[i,f]>0 ? exp(s2) : 0, EB2 = adj[i,f]>0 ? exp(0.2*s2) : 0
// Identity: exp(leakyrelu(s1+s2)) = max(EA1*EB1, EA2*EB2); mask -> exact 0.
// ---------------------------------------------------------------------------
__global__ __launch_bounds__(256) void gat_prep(
    const float* __restrict__ h, const float* __restrict__ adj,
    const float* __restrict__ W, const float* __restrict__ a,
    float* __restrict__ Wh, float* __restrict__ EA1, float* __restrict__ EA2,
    float* __restrict__ EB1, float* __restrict__ EB2)
{
    const int t = threadIdx.x;
    const int f = t & 63;
    const int i = (blockIdx.x << 2) + (t >> 6);   // wave-uniform row

    const float* __restrict__ hrow = h + i * 128;
    const float* __restrict__ arow = adj + i * 64;

    float wh = 0.0f;
    #pragma unroll 8
    for (int k = 0; k < 128; ++k) wh = fmaf(hrow[k], W[k * 64 + f], wh);
    Wh[i * 64 + f] = wh;

    float v1 = 0.0f, v2 = 0.0f;
    #pragma unroll 8
    for (int k = 0; k < 64; ++k) {
        const float av = arow[k];
        v1 = fmaf(av, a[k * 64 + f], v1);
        v2 = fmaf(av, a[(64 + k) * 64 + f], v2);
    }
    EA1[i * 64 + f] = __expf(v1);
    EA2[i * 64 + f] = __expf(0.2f * v1);
    const bool m = arow[f] > 0.0f;                // source-node mask adj[j,f]>0
    EB1[i * 64 + f] = m ? __expf(v2) : 0.0f;
    EB2[i * 64 + f] = m ? __expf(0.2f * v2) : 0.0f;
}

// ---------------------------------------------------------------------------
// Main (512 blocks x 512 thr): block handles TWO destination rows i0,i1.
// Pass 1: Z[r][f] = sum_j max(EA1*EB1, EA2*EB2)  (loads only — no vmcnt hazard)
// Pass 2: DEPTH-2 SOFTWARE PIPELINE. Per half-step: compute from bank regs
// (VALU only) -> issue prefetch loads for jb+64 -> issue streaming stores.
// Loads are thus always OLDER than any pending store in the in-order vmcnt
// queue, so load-use waits (vmcnt(7)) never block on HBM store drain.
// ---------------------------------------------------------------------------
__global__ __launch_bounds__(512, 4) void gat_attn(
    const float* __restrict__ EA1, const float* __restrict__ EA2,
    const float* __restrict__ EB1, const float* __restrict__ EB2,
    const float* __restrict__ Wh,
    float* __restrict__ out_hp, float* __restrict__ out_att)
{
    __shared__ float red[2][32][64];
    __shared__ float zinv[2][64];

    const int t  = threadIdx.x;
    const int fg = t & 15;
    const int jo = t >> 4;          // 0..31
    const int fb = fg << 2;
    const int i0 = blockIdx.x << 1;

    const f32x4 a1r0 = *reinterpret_cast<const f32x4*>(EA1 + (i0 + 0) * 64 + fb);
    const f32x4 a2r0 = *reinterpret_cast<const f32x4*>(EA2 + (i0 + 0) * 64 + fb);
    const f32x4 a1r1 = *reinterpret_cast<const f32x4*>(EA1 + (i0 + 1) * 64 + fb);
    const f32x4 a2r1 = *reinterpret_cast<const f32x4*>(EA2 + (i0 + 1) * 64 + fb);

    // ---- pass 1: Z for both rows (pure loads, no stores) ----
    f32x4 z0 = {0.f, 0.f, 0.f, 0.f};
    f32x4 z1 = {0.f, 0.f, 0.f, 0.f};
    #pragma unroll 4
    for (int jb = 0; jb < 1024; jb += 32) {
        const int j = jb + jo;
        const f32x4 b1 = *reinterpret_cast<const f32x4*>(EB1 + j * 64 + fb);
        const f32x4 b2 = *reinterpret_cast<const f32x4*>(EB2 + j * 64 + fb);
        z0.x += fmaxf(a1r0.x * b1.x, a2r0.x * b2.x);
        z0.y += fmaxf(a1r0.y * b1.y, a2r0.y * b2.y);
        z0.z += fmaxf(a1r0.z * b1.z, a2r0.z * b2.z);
        z0.w += fmaxf(a1r0.w * b1.w, a2r0.w * b2.w);
        z1.x += fmaxf(a1r1.x * b1.x, a2r1.x * b2.x);
        z1.y += fmaxf(a1r1.y * b1.y, a2r1.y * b2.y);
        z1.z += fmaxf(a1r1.z * b1.z, a2r1.z * b2.z);
        z1.w += fmaxf(a1r1.w * b1.w, a2r1.w * b2.w);
    }
    *reinterpret_cast<f32x4*>(&red[0][jo][fb]) = z0;
    *reinterpret_cast<f32x4*>(&red[1][jo][fb]) = z1;
    __syncthreads();
    if (t < 128) {
        const int r = t >> 6, f = t & 63;
        float z = 0.0f;
        #pragma unroll
        for (int o = 0; o < 32; ++o) z += red[r][o][f];
        zinv[r][f] = 1.0f / z;
    }
    __syncthreads();

    f32x4 s1r0, s2r0, s1r1, s2r1;   // fold 1/Z into per-row terms once
    {
        const f32x4 v0 = *reinterpret_cast<const f32x4*>(&zinv[0][fb]);
        const f32x4 v1 = *reinterpret_cast<const f32x4*>(&zinv[1][fb]);
        s1r0.x = a1r0.x * v0.x; s1r0.y = a1r0.y * v0.y; s1r0.z = a1r0.z * v0.z; s1r0.w = a1r0.w * v0.w;
        s2r0.x = a2r0.x * v0.x; s2r0.y = a2r0.y * v0.y; s2r0.z = a2r0.z * v0.z; s2r0.w = a2r0.w * v0.w;
        s1r1.x = a1r1.x * v1.x; s1r1.y = a1r1.y * v1.y; s1r1.z = a1r1.z * v1.z; s1r1.w = a1r1.w * v1.w;
        s2r1.x = a2r1.x * v1.x; s2r1.y = a2r1.y * v1.y; s2r1.z = a2r1.z * v1.z; s2r1.w = a2r1.w * v1.w;
    }

    // ---- pass 2: depth-2 pipelined stream ----
    f32x4 h0 = {0.f, 0.f, 0.f, 0.f};
    f32x4 h1 = {0.f, 0.f, 0.f, 0.f};
    float* __restrict__ o0 = out_att + (size_t)(i0 + 0) * 65536 + fb;
    float* __restrict__ o1 = out_att + (size_t)(i0 + 1) * 65536 + fb;

    const int jbase = jo * 64 + fb;               // element offset of (jo, fb)

    // prologue: bank A <- jb=0, bank B <- jb=32
    f32x4 b1A = *reinterpret_cast<const f32x4*>(EB1 + jbase);
    f32x4 b2A = *reinterpret_cast<const f32x4*>(EB2 + jbase);
    f32x4 wvA = *reinterpret_cast<const f32x4*>(Wh  + jbase);
    f32x4 b1B = *reinterpret_cast<const f32x4*>(EB1 + jbase + 32 * 64);
    f32x4 b2B = *reinterpret_cast<const f32x4*>(EB2 + jbase + 32 * 64);
    f32x4 wvB = *reinterpret_cast<const f32x4*>(Wh  + jbase + 32 * 64);

    for (int jb = 0; jb < 1024; jb += 64) {
        // ---- half-step A: consumes jb, prefetches jb+64 ----
        {
            f32x4 oA, oB;
            oA.x = fmaxf(s1r0.x * b1A.x, s2r0.x * b2A.x);
            oA.y = fmaxf(s1r0.y * b1A.y, s2r0.y * b2A.y);
            oA.z = fmaxf(s1r0.z * b1A.z, s2r0.z * b2A.z);
            oA.w = fmaxf(s1r0.w * b1A.w, s2r0.w * b2A.w);
            oB.x = fmaxf(s1r1.x * b1A.x, s2r1.x * b2A.x);
            oB.y = fmaxf(s1r1.y * b1A.y, s2r1.y * b2A.y);
            oB.z = fmaxf(s1r1.z * b1A.z, s2r1.z * b2A.z);
            oB.w = fmaxf(s1r1.w * b1A.w, s2r1.w * b2A.w);
            h0.x = fmaf(oA.x, wvA.x, h0.x); h0.y = fmaf(oA.y, wvA.y, h0.y);
            h0.z = fmaf(oA.z, wvA.z, h0.z); h0.w = fmaf(oA.w, wvA.w, h0.w);
            h1.x = fmaf(oB.x, wvA.x, h1.x); h1.y = fmaf(oB.y, wvA.y, h1.y);
            h1.z = fmaf(oB.z, wvA.z, h1.z); h1.w = fmaf(oB.w, wvA.w, h1.w);
            // prefetch jb+64 into bank A (loads issued BEFORE this step's stores;
            // index wraps on last iter -> harmless dummy load of row block 0)
            const int jpA = (jb + 64) & 1023;
            b1A = *reinterpret_cast<const f32x4*>(EB1 + jpA * 64 + jbase);
            b2A = *reinterpret_cast<const f32x4*>(EB2 + jpA * 64 + jbase);
            wvA = *reinterpret_cast<const f32x4*>(Wh  + jpA * 64 + jbase);
            *reinterpret_cast<f32x4*>(o0 + (jb)*64 + jo * 64) = oA;
            *reinterpret_cast<f32x4*>(o1 + (jb)*64 + jo * 64) = oB;
        }
        // ---- half-step B: consumes jb+32, prefetches jb+96 ----
        {
            f32x4 oA, oB;
            oA.x = fmaxf(s1r0.x * b1B.x, s2r0.x * b2B.x);
            oA.y = fmaxf(s1r0.y * b1B.y, s2r0.y * b2B.y);
            oA.z = fmaxf(s1r0.z * b1B.z, s2r0.z * b2B.z);
            oA.w = fmaxf(s1r0.w * b1B.w, s2r0.w * b2B.w);
            oB.x = fmaxf(s1r1.x * b1B.x, s2r1.x * b2B.x);
            oB.y = fmaxf(s1r1.y * b1B.y, s2r1.y * b2B.y);
            oB.z = fmaxf(s1r1.z * b1B.z, s2r1.z * b2B.z);
            oB.w = fmaxf(s1r1.w * b1B.w, s2r1.w * b2B.w);
            h0.x = fmaf(oA.x, wvB.x, h0.x); h0.y = fmaf(oA.y, wvB.y, h0.y);
            h0.z = fmaf(oA.z, wvB.z, h0.z); h0.w = fmaf(oA.w, wvB.w, h0.w);
            h1.x = fmaf(oB.x, wvB.x, h1.x); h1.y = fmaf(oB.y, wvB.y, h1.y);
            h1.z = fmaf(oB.z, wvB.z, h1.z); h1.w = fmaf(oB.w, wvB.w, h1.w);
            const int jpB = (jb + 96) & 1023;
            b1B = *reinterpret_cast<const f32x4*>(EB1 + jpB * 64 + jbase);
            b2B = *reinterpret_cast<const f32x4*>(EB2 + jpB * 64 + jbase);
            wvB = *reinterpret_cast<const f32x4*>(Wh  + jpB * 64 + jbase);
            *reinterpret_cast<f32x4*>(o0 + (jb + 32) * 64 + jo * 64) = oA;
            *reinterpret_cast<f32x4*>(o1 + (jb + 32) * 64 + jo * 64) = oB;
        }
    }

    *reinterpret_cast<f32x4*>(&red[0][jo][fb]) = h0;   // safe: after barrier 2
    *reinterpret_cast<f32x4*>(&red[1][jo][fb]) = h1;
    __syncthreads();
    if (t < 128) {
        const int r = t >> 6, f = t & 63;
        float v = 0.0f;
        #pragma unroll
        for (int o = 0; o < 32; ++o) v += red[r][o][f];
        out_hp[(i0 + r) * 64 + f] = (v > 0.0f) ? v : expm1f(v);
    }
}

extern "C" void kernel_launch(void* const* d_in, const int* in_sizes, int n_in,
                              void* d_out, int out_size, void* d_ws, size_t ws_size,
                              hipStream_t stream) {
    const float* h   = (const float*)d_in[0];   // (1024, 128)
    const float* adj = (const float*)d_in[1];   // (1024, 64)
    const float* W   = (const float*)d_in[2];   // (128, 64)
    const float* a   = (const float*)d_in[3];   // (128, 64)

    float* ws  = (float*)d_ws;                  // 1.25 MiB scratch used
    float* Wh  = ws;                            // (1024, 64)
    float* EA1 = ws + 65536;
    float* EA2 = ws + 131072;
    float* EB1 = ws + 196608;
    float* EB2 = ws + 262144;

    float* out     = (float*)d_out;
    float* out_hp  = out;                       // elu(h_prime): 65536 floats
    float* out_att = out + 65536;               // attention: 1024*1024*64

    gat_prep<<<256, 256, 0, stream>>>(h, adj, W, a, Wh, EA1, EA2, EB1, EB2);
    gat_attn<<<512, 512, 0, stream>>>(EA1, EA2, EB1, EB2, Wh, out_hp, out_att);
}